// Round 6
// baseline (18314.067 us; speedup 1.0000x reference)
//
#include <hip/hip_runtime.h>
#include <hip/hip_fp16.h>
#include <stdint.h>
#include <stddef.h>

typedef _Float16 f16;
typedef _Float16 f16x4 __attribute__((ext_vector_type(4)));
typedef _Float16 f16x8 __attribute__((ext_vector_type(8)));
typedef float f32x4 __attribute__((ext_vector_type(4)));

#define SEQL 512
#define NBATCH 64
#define KIN 38
#define KPAD 64
#define EMB 1024
#define HID 1024
#define G3 3072
#define MALL (SEQL*NBATCH)   // 32768
#define NCLS 38
#define WPAD 1032            // 1024 + 8 f16 pad
#define FS 32                // flag stride in ints (128B line separation)

// ---------------- conversion / prep kernels ----------------

__global__ void k_cvt(const float* __restrict__ s, f16* __restrict__ d, long n) {
  long i = (long)blockIdx.x * blockDim.x + threadIdx.x;
  long stride = (long)gridDim.x * blockDim.x;
  for (; i < n; i += stride) d[i] = (f16)s[i];
}

__global__ void k_zero(int* __restrict__ p, int n) {
  int i = blockIdx.x * 256 + threadIdx.x;
  if (i < n) p[i] = 0;
}

__global__ void k_outw_pad(const float* __restrict__ s, f16* __restrict__ d) {
  int i = blockIdx.x * 256 + threadIdx.x;   // 128*1024
  if (i >= 128 * 1024) return;
  int r = i >> 10, c = i & 1023;
  d[i] = (r < NCLS) ? (f16)s[r * 1024 + c] : (f16)0.f;
}

__global__ void k_cvt_in(const float* __restrict__ s, f16* __restrict__ d) {
  int i = blockIdx.x * 256 + threadIdx.x;   // 32768*64
  if (i >= MALL * KPAD) return;
  int m = i >> 6, k = i & 63;
  d[i] = (k < KIN) ? (f16)s[m * KIN + k] : (f16)0.f;
}

__global__ void k_prep_w0(const float* __restrict__ wih0, const float* __restrict__ embW,
                          f16* __restrict__ w0) {
  int i = blockIdx.x * 256 + threadIdx.x;   // 3072*64
  if (i >= G3 * KPAD) return;
  int g = i >> 6, k = i & 63;
  float sacc = 0.f;
  if (k < KIN) {
    for (int e = 0; e < EMB; ++e) sacc += wih0[g * EMB + e] * embW[e * KIN + k];
  }
  w0[i] = (f16)sacc;
}

__global__ void k_prep_b0(const float* __restrict__ wih0, const float* __restrict__ embB,
                          const float* __restrict__ bih0, float* __restrict__ b0) {
  int g = blockIdx.x * 256 + threadIdx.x;
  if (g >= G3) return;
  float sacc = bih0[g];
  for (int e = 0; e < EMB; ++e) sacc += wih0[g * EMB + e] * embB[e];
  b0[g] = sacc;
}

// ---------------- GEMM: C = A @ B^T + bias ----------------
// Output modes: C16 row-major fp16 | C16T transposed fp16 (C^T[col][row], 8B
// packed stores along rows) | C32 row-major fp32.

__global__ __launch_bounds__(256) void k_gemm(
    const f16* __restrict__ A, const f16* __restrict__ B,
    const float* __restrict__ bias,
    f16* __restrict__ C16, f16* __restrict__ C16T, float* __restrict__ C32,
    int K, int nvalid, int ldc) {
  __shared__ f16 As[128][40];
  __shared__ f16 Bs[128][40];
  const int tid = threadIdx.x;
  const long brow = (long)blockIdx.x * 128;
  const long bcol = (long)blockIdx.y * 128;
  const int w = tid >> 6, lane = tid & 63;
  const int lr = lane & 15, kg = lane >> 4;
  const int wr = w >> 1, wc = w & 1;

  f32x4 acc[4][4] = {};

  for (int kk = 0; kk < K; kk += 32) {
    __syncthreads();
#pragma unroll
    for (int p = 0; p < 2; ++p) {
      int idx = p * 256 + tid;
      int row = idx >> 2, seg = idx & 3;
      *(float4*)(&As[row][seg * 8]) = *(const float4*)(&A[(brow + row) * K + kk + seg * 8]);
      *(float4*)(&Bs[row][seg * 8]) = *(const float4*)(&B[(bcol + row) * K + kk + seg * 8]);
    }
    __syncthreads();
    f16x8 af[4], bf[4];
#pragma unroll
    for (int i = 0; i < 4; ++i) af[i] = *(const f16x8*)(&As[wr * 64 + i * 16 + lr][kg * 8]);
#pragma unroll
    for (int j = 0; j < 4; ++j) bf[j] = *(const f16x8*)(&Bs[wc * 64 + j * 16 + lr][kg * 8]);
#pragma unroll
    for (int i = 0; i < 4; ++i)
#pragma unroll
      for (int j = 0; j < 4; ++j)
        acc[i][j] = __builtin_amdgcn_mfma_f32_16x16x32_f16(af[i], bf[j], acc[i][j], 0, 0, 0);
  }

#pragma unroll
  for (int j = 0; j < 4; ++j) {
    int col = (int)bcol + wc * 64 + j * 16 + lr;
    float bv = (col < nvalid) ? bias[col] : 0.f;
#pragma unroll
    for (int i = 0; i < 4; ++i) {
      if (C16T) {
        f16x4 pk;
#pragma unroll
        for (int r = 0; r < 4; ++r) pk[r] = (f16)(acc[i][j][r] + bv);
        long row = brow + wr * 64 + i * 16 + kg * 4;
        *(f16x4*)&C16T[(size_t)col * ldc + row] = pk;
      } else {
#pragma unroll
        for (int r = 0; r < 4; ++r) {
          long row = brow + wr * 64 + i * 16 + kg * 4 + r;
          float v = acc[i][j][r] + bv;
          if (C16) C16[row * ldc + col] = (f16)v;
          else if (col < nvalid) C32[row * ldc + col] = v;
        }
      }
    }
  }
}

// ---------------- persistent GRU recurrence: T steps per launch ----------------
// 64 blocks (1/CU). Block g owns hidden cols j0=g*16; 48 w_hh rows in LDS.
// Per step: wait (per-block flags), issue ALL 32 h-frag loads + 4 hp loads
// (one round trip), 96 MFMAs, gates in-register (xgT pre-loaded across the
// barrier as 3x f16x4), store private hbuf slice, __syncthreads, release own
// flag, THEN store xseq row (off critical path) and prefetch next xgT.

__global__ __launch_bounds__(256, 1) void k_rnn(
    f16* __restrict__ xseq,          // [SEQL*64][1024] layer outputs
    f16* __restrict__ hbuf,          // [2][64][64][16] ping-pong ([kblk][m][klo])
    const f16* __restrict__ xgT,     // [3072][T*64] transposed input projections
    const f16* __restrict__ whhl,    // [3072][1024] fp16
    const float* __restrict__ bhhl,  // [3072]
    int t0, int T, int LDT, int base,
    int* __restrict__ flags) {       // 64 flags, 128B apart
  __shared__ f16 wlds[48 * WPAD];    // ~99KB
  const int g = blockIdx.x, j0 = g * 16, tid = threadIdx.x;
  const int w = tid >> 6, lane = tid & 63, lr = lane & 15, kg = lane >> 4;

  for (int idx = tid; idx < 48 * 128; idx += 256) {
    int row = idx >> 7, seg = idx & 127;
    int gt = row >> 4, r = row & 15;
    *(f16x8*)&wlds[row * WPAD + seg * 8] =
        *(const f16x8*)&whhl[(size_t)((gt << 10) + j0 + r) * HID + seg * 8];
  }
  __syncthreads();

  const int j = j0 + lr;
  const float br = bhhl[j], bz = bhhl[1024 + j], bn = bhhl[2048 + j];
  const f16* wr_ = &wlds[(0 * 16 + lr) * WPAD];
  const f16* wz_ = &wlds[(1 * 16 + lr) * WPAD];
  const f16* wn_ = &wlds[(2 * 16 + lr) * WPAD];
  const int mq = 16 * w + kg * 4;    // this thread's 4-row m group

  // prefetch xgT for first step: 3 gates x 4 consecutive m
  f16x4 px[3];
#pragma unroll
  for (int gt = 0; gt < 3; ++gt)
    px[gt] = *(const f16x4*)&xgT[(size_t)((gt << 10) + j) * LDT + mq];

  for (int tt = 0; tt < T; ++tt) {
    const int t = t0 + tt;
    f32x4 ar = {}, az = {}, an = {};
    float hp4[4] = {0.f, 0.f, 0.f, 0.f};
    if (t > 0) {
      const int target = base + t;
      int v;
      do {
        v = __hip_atomic_load(&flags[lane * FS], __ATOMIC_ACQUIRE, __HIP_MEMORY_SCOPE_AGENT);
      } while (!__all(v >= target));
      const f16* hb = hbuf + (((t & 1) ^ 1) ? (size_t)(NBATCH * HID) : 0);
      // issue ALL loads up front: 32 A-frags + 4 hp scalars -> one round trip
      const f16* hbase = hb + (16 * w + lr) * 16 + (kg & 1) * 8 + (kg >> 1) * 1024;
      const f16* hbp = hb + g * 1024;
      f16x8 fa[16], fb[16];
#pragma unroll
      for (int kc = 0; kc < 16; ++kc) fa[kc] = *(const f16x8*)(hbase + kc * 2048);
#pragma unroll
      for (int kc = 0; kc < 16; ++kc) fb[kc] = *(const f16x8*)(hbase + (kc + 16) * 2048);
#pragma unroll
      for (int r = 0; r < 4; ++r) hp4[r] = (float)hbp[(mq + r) * 16 + lr];
#pragma unroll
      for (int kc = 0; kc < 16; ++kc) {
        int ko = kc * 32 + kg * 8;
        ar = __builtin_amdgcn_mfma_f32_16x16x32_f16(fa[kc], *(const f16x8*)(wr_ + ko), ar, 0, 0, 0);
        az = __builtin_amdgcn_mfma_f32_16x16x32_f16(fa[kc], *(const f16x8*)(wz_ + ko), az, 0, 0, 0);
        an = __builtin_amdgcn_mfma_f32_16x16x32_f16(fa[kc], *(const f16x8*)(wn_ + ko), an, 0, 0, 0);
      }
#pragma unroll
      for (int kc = 0; kc < 16; ++kc) {
        int ko = (kc + 16) * 32 + kg * 8;
        ar = __builtin_amdgcn_mfma_f32_16x16x32_f16(fb[kc], *(const f16x8*)(wr_ + ko), ar, 0, 0, 0);
        az = __builtin_amdgcn_mfma_f32_16x16x32_f16(fb[kc], *(const f16x8*)(wz_ + ko), az, 0, 0, 0);
        an = __builtin_amdgcn_mfma_f32_16x16x32_f16(fb[kc], *(const f16x8*)(wn_ + ko), an, 0, 0, 0);
      }
    }
    f16* hbn = hbuf + ((t & 1) ? (size_t)(NBATCH * HID) : 0) + g * 1024;
    f16 hv4[4];
#pragma unroll
    for (int r = 0; r < 4; ++r) {
      float xr = (float)px[0][r], xz = (float)px[1][r], xn = (float)px[2][r];
      float rr = 1.f / (1.f + __expf(-(xr + ar[r] + br)));
      float zz = 1.f / (1.f + __expf(-(xz + az[r] + bz)));
      float pre = xn + rr * (an[r] + bn);
      float nn = 2.f / (1.f + __expf(-2.f * pre)) - 1.f;   // tanh
      float hv = (1.f - zz) * nn + zz * hp4[r];
      hv4[r] = (f16)hv;
      hbn[(mq + r) * 16 + lr] = hv4[r];
    }
    __syncthreads();                 // drains hbuf stores of all waves
    if (tid == 0)
      __hip_atomic_store(&flags[g * FS], base + t + 1, __ATOMIC_RELEASE,
                         __HIP_MEMORY_SCOPE_AGENT);
    // off critical path: layer-output store + next-step xgT prefetch
    f16* xrow = xseq + (size_t)t * (NBATCH * HID);
#pragma unroll
    for (int r = 0; r < 4; ++r) xrow[(mq + r) * HID + j] = hv4[r];
    if (tt + 1 < T) {
      const int mq2 = (tt + 1) * 64 + mq;
#pragma unroll
      for (int gt = 0; gt < 3; ++gt)
        px[gt] = *(const f16x4*)&xgT[(size_t)((gt << 10) + j) * LDT + mq2];
    }
  }
}

// ---------------- launch ----------------

extern "C" void kernel_launch(void* const* d_in, const int* in_sizes, int n_in,
                              void* d_out, int out_size, void* d_ws, size_t ws_size,
                              hipStream_t stream) {
  const float* in   = (const float*)d_in[0];
  const float* embW = (const float*)d_in[1];
  const float* embB = (const float*)d_in[2];
  const float* wih  = (const float*)d_in[3];
  const float* whh  = (const float*)d_in[4];
  const float* bih  = (const float*)d_in[5];
  const float* bhh  = (const float*)d_in[6];
  const float* outW = (const float*)d_in[7];
  const float* outB = (const float*)d_in[8];
  float* out = (float*)d_out;

  char* ws = (char*)d_ws;
  size_t off = 0;
  auto alloc = [&](size_t bytes) -> void* {
    void* p = ws + off; off += (bytes + 255) & ~(size_t)255; return p;
  };
  f16* whhL   = (f16*)alloc((size_t)G3 * HID * 2);    // 6 MB, re-converted per layer
  f16* wihL   = (f16*)alloc((size_t)G3 * HID * 2);    // 6 MB, layers 1,2
  f16* w016   = (f16*)alloc((size_t)G3 * KPAD * 2);
  f16* outw16 = (f16*)alloc(128UL * HID * 2);
  float* b0   = (float*)alloc((size_t)G3 * 4);
  f16* in16   = (f16*)alloc((size_t)MALL * KPAD * 2); // 4 MB
  f16* xseq   = (f16*)alloc((size_t)MALL * HID * 2);  // 64 MB, in-place across layers
  f16* hbuf   = (f16*)alloc(2UL * NBATCH * HID * 2);  // 256 KB ping-pong
  int* flags  = (int*)alloc(64UL * FS * 4);           // 8 KB per-block flags
  size_t fixed = off;

  int T = 128;
  while (T > 2 && fixed + ((size_t)T * NBATCH * G3 * 2 + 256) > ws_size) T >>= 1;
  f16* xgT = (f16*)alloc((size_t)T * NBATCH * G3 * 2);   // [3072][T*64]
  if (off > ws_size) return;
  const int NCHUNK = SEQL / T;
  const int LDT = T * NBATCH;

  // ---- prep ----
  k_zero<<<(64 * FS + 255) / 256, 256, 0, stream>>>(flags, 64 * FS);
  k_outw_pad<<<512, 256, 0, stream>>>(outW, outw16);
  k_cvt_in<<<(MALL * KPAD + 255) / 256, 256, 0, stream>>>(in, in16);
  k_prep_w0<<<(G3 * KPAD + 255) / 256, 256, 0, stream>>>(wih, embW, w016);
  k_prep_b0<<<(G3 + 255) / 256, 256, 0, stream>>>(wih, embB, bih, b0);

  for (int l = 0; l < 3; ++l) {
    k_cvt<<<2048, 256, 0, stream>>>(whh + (size_t)l * G3 * HID, whhL, (long)G3 * HID);
    if (l > 0)
      k_cvt<<<2048, 256, 0, stream>>>(wih + (size_t)l * G3 * EMB, wihL, (long)G3 * HID);

    for (int c = 0; c < NCHUNK; ++c) {
      if (l == 0)
        k_gemm<<<dim3(T * NBATCH / 128, G3 / 128), 256, 0, stream>>>(
            in16 + (size_t)c * T * NBATCH * KPAD, w016, b0,
            nullptr, xgT, nullptr, KPAD, G3, LDT);
      else
        k_gemm<<<dim3(T * NBATCH / 128, G3 / 128), 256, 0, stream>>>(
            xseq + (size_t)c * T * NBATCH * HID, wihL, bih + l * G3,
            nullptr, xgT, nullptr, HID, G3, LDT);
      k_rnn<<<64, 256, 0, stream>>>(xseq, hbuf, xgT, whhL, bhh + l * G3,
                                    c * T, T, LDT, l * SEQL, flags);
    }
  }
  // logits = xseq @ out_W^T + out_b (fp32 out)
  k_gemm<<<dim3(MALL / 128, 1), 256, 0, stream>>>(xseq, outw16, outB,
                                                  nullptr, nullptr, out, HID, NCLS, NCLS);
}

// Round 8
// 14458.356 us; speedup vs baseline: 1.2667x; 1.2667x over previous
//
#include <hip/hip_runtime.h>
#include <hip/hip_fp16.h>
#include <stdint.h>
#include <stddef.h>

typedef _Float16 f16;
typedef _Float16 f16x4 __attribute__((ext_vector_type(4)));
typedef _Float16 f16x8 __attribute__((ext_vector_type(8)));
typedef float f32x4 __attribute__((ext_vector_type(4)));
typedef unsigned long long u64;

#define SEQL 512
#define NBATCH 64
#define KIN 38
#define KPAD 64
#define EMB 1024
#define HID 1024
#define G3 3072
#define MALL_M (SEQL*NBATCH)  // 32768
#define NCLS 38
#define WPAD 1032             // 1024 + 8 f16 pad
#define FS 32                 // flag stride in ints (128B line separation)

// ---------------- conversion / prep kernels ----------------

__global__ void k_cvt(const float* __restrict__ s, f16* __restrict__ d, long n) {
  long i = (long)blockIdx.x * blockDim.x + threadIdx.x;
  long stride = (long)gridDim.x * blockDim.x;
  for (; i < n; i += stride) d[i] = (f16)s[i];
}

__global__ void k_zero(int* __restrict__ p, int n) {
  int i = blockIdx.x * 256 + threadIdx.x;
  if (i < n) p[i] = 0;
}

__global__ void k_outw_pad(const float* __restrict__ s, f16* __restrict__ d) {
  int i = blockIdx.x * 256 + threadIdx.x;   // 128*1024
  if (i >= 128 * 1024) return;
  int r = i >> 10, c = i & 1023;
  d[i] = (r < NCLS) ? (f16)s[r * 1024 + c] : (f16)0.f;
}

__global__ void k_cvt_in(const float* __restrict__ s, f16* __restrict__ d) {
  int i = blockIdx.x * 256 + threadIdx.x;   // 32768*64
  if (i >= MALL_M * KPAD) return;
  int m = i >> 6, k = i & 63;
  d[i] = (k < KIN) ? (f16)s[m * KIN + k] : (f16)0.f;
}

__global__ void k_prep_w0(const float* __restrict__ wih0, const float* __restrict__ embW,
                          f16* __restrict__ w0) {
  int i = blockIdx.x * 256 + threadIdx.x;   // 3072*64
  if (i >= G3 * KPAD) return;
  int g = i >> 6, k = i & 63;
  float sacc = 0.f;
  if (k < KIN) {
    for (int e = 0; e < EMB; ++e) sacc += wih0[g * EMB + e] * embW[e * KIN + k];
  }
  w0[i] = (f16)sacc;
}

__global__ void k_prep_b0(const float* __restrict__ wih0, const float* __restrict__ embB,
                          const float* __restrict__ bih0, float* __restrict__ b0) {
  int g = blockIdx.x * 256 + threadIdx.x;
  if (g >= G3) return;
  float sacc = bih0[g];
  for (int e = 0; e < EMB; ++e) sacc += wih0[g * EMB + e] * embB[e];
  b0[g] = sacc;
}

// ---------------- GEMM: C = A @ B^T + bias ----------------
// Output modes: C16 row-major fp16 | C16T transposed fp16 | C32 row-major fp32.

__global__ __launch_bounds__(256) void k_gemm(
    const f16* __restrict__ A, const f16* __restrict__ B,
    const float* __restrict__ bias,
    f16* __restrict__ C16, f16* __restrict__ C16T, float* __restrict__ C32,
    int K, int nvalid, int ldc) {
  __shared__ f16 As[128][40];
  __shared__ f16 Bs[128][40];
  const int tid = threadIdx.x;
  const long brow = (long)blockIdx.x * 128;
  const long bcol = (long)blockIdx.y * 128;
  const int w = tid >> 6, lane = tid & 63;
  const int lr = lane & 15, kg = lane >> 4;
  const int wr = w >> 1, wc = w & 1;

  f32x4 acc[4][4] = {};

  for (int kk = 0; kk < K; kk += 32) {
    __syncthreads();
#pragma unroll
    for (int p = 0; p < 2; ++p) {
      int idx = p * 256 + tid;
      int row = idx >> 2, seg = idx & 3;
      *(float4*)(&As[row][seg * 8]) = *(const float4*)(&A[(brow + row) * K + kk + seg * 8]);
      *(float4*)(&Bs[row][seg * 8]) = *(const float4*)(&B[(bcol + row) * K + kk + seg * 8]);
    }
    __syncthreads();
    f16x8 af[4], bf[4];
#pragma unroll
    for (int i = 0; i < 4; ++i) af[i] = *(const f16x8*)(&As[wr * 64 + i * 16 + lr][kg * 8]);
#pragma unroll
    for (int j = 0; j < 4; ++j) bf[j] = *(const f16x8*)(&Bs[wc * 64 + j * 16 + lr][kg * 8]);
#pragma unroll
    for (int i = 0; i < 4; ++i)
#pragma unroll
      for (int j = 0; j < 4; ++j)
        acc[i][j] = __builtin_amdgcn_mfma_f32_16x16x32_f16(af[i], bf[j], acc[i][j], 0, 0, 0);
  }

#pragma unroll
  for (int j = 0; j < 4; ++j) {
    int col = (int)bcol + wc * 64 + j * 16 + lr;
    float bv = (col < nvalid) ? bias[col] : 0.f;
#pragma unroll
    for (int i = 0; i < 4; ++i) {
      if (C16T) {
        f16x4 pk;
#pragma unroll
        for (int r = 0; r < 4; ++r) pk[r] = (f16)(acc[i][j][r] + bv);
        long row = brow + wr * 64 + i * 16 + kg * 4;
        *(f16x4*)&C16T[(size_t)col * ldc + row] = pk;
      } else {
#pragma unroll
        for (int r = 0; r < 4; ++r) {
          long row = brow + wr * 64 + i * 16 + kg * 4 + r;
          float v = acc[i][j][r] + bv;
          if (C16) C16[row * ldc + col] = (f16)v;
          else if (col < nvalid) C32[row * ldc + col] = v;
        }
      }
    }
  }
}

// ---------------- persistent GRU recurrence ----------------
// 64 blocks (1/CU). Block g owns hidden cols j0=g*16; 48 w_hh rows in LDS.
// Sync protocol (agent-scope release/acquire, ONE fence each side per step):
//   producer: plain h stores -> __syncthreads (vmcnt drained) ->
//             tid0 fence(RELEASE,"agent") (wbL2) -> relaxed flag store
//   consumer: wave0 spins with RELAXED flag loads -> wave0
//             fence(ACQUIRE,"agent") (invL2) -> __syncthreads -> plain h loads
// hp carried in registers; reloaded from hbuf at chunk boundaries (t0>0).
// xseq stores + xgT prefetch placed after the release (off critical path).

__global__ __launch_bounds__(256, 1) void k_rnn(
    f16* __restrict__ xseq,          // [SEQL*64][1024] layer outputs
    f16* __restrict__ hbuf,          // [2][64 kblk][64 m][16 klo] f16 ping-pong
    const f16* __restrict__ xgT,     // [3072][T*64] transposed input projections
    const f16* __restrict__ whhl,    // [3072][1024] fp16
    const float* __restrict__ bhhl,  // [3072]
    int t0, int T, int LDT, int base,
    int* __restrict__ flags) {       // 64 flags, 128B apart
  __shared__ f16 wlds[48 * WPAD];    // ~99KB
  __shared__ f16 hstage[NBATCH][16]; // 2KB repack stage
  const int g = blockIdx.x, j0 = g * 16, tid = threadIdx.x;
  const int w = tid >> 6, lane = tid & 63, lr = lane & 15, kg = lane >> 4;

  for (int idx = tid; idx < 48 * 128; idx += 256) {
    int row = idx >> 7, seg = idx & 127;
    int gt = row >> 4, r = row & 15;
    *(f16x8*)&wlds[row * WPAD + seg * 8] =
        *(const f16x8*)&whhl[(size_t)((gt << 10) + j0 + r) * HID + seg * 8];
  }
  __syncthreads();

  const int j = j0 + lr;
  const float br = bhhl[j], bz = bhhl[1024 + j], bn = bhhl[2048 + j];
  const f16* wr_ = &wlds[(0 * 16 + lr) * WPAD];
  const f16* wz_ = &wlds[(1 * 16 + lr) * WPAD];
  const f16* wn_ = &wlds[(2 * 16 + lr) * WPAD];
  const int mq = 16 * w + kg * 4;    // this thread's 4-row m group
  const int ms = tid >> 2, seg4 = (tid & 3) * 4;   // repack task: m=ms, klo=seg4..+4

  // prefetch xgT for first step
  f16x4 px[3];
#pragma unroll
  for (int gt = 0; gt < 3; ++gt)
    px[gt] = *(const f16x4*)&xgT[(size_t)((gt << 10) + j) * LDT + mq];

  float hp4[4] = {0.f, 0.f, 0.f, 0.f};   // register-carried h_{t-1}[mq+r][j]

  for (int tt = 0; tt < T; ++tt) {
    const int t = t0 + tt;
    f32x4 ar = {}, az = {}, an = {};
    if (t > 0) {
      if (w == 0) {
        const int target = base + t;
        int v;
        do {
          v = __hip_atomic_load(&flags[lane * FS], __ATOMIC_RELAXED, __HIP_MEMORY_SCOPE_AGENT);
        } while (!__all(v >= target));
        __builtin_amdgcn_fence(__ATOMIC_ACQUIRE, "agent");   // one invL2 per block-step
      }
      __syncthreads();                 // all waves see invalidated caches
      const f16* hb = hbuf + (((t & 1) ^ 1) ? (size_t)(NBATCH * HID) : 0);
      if (tt == 0) {                   // chunk boundary: reload carried h_prev
        const f16* hbp = hb + g * 1024;
#pragma unroll
        for (int r = 0; r < 4; ++r) hp4[r] = (float)hbp[(mq + r) * 16 + lr];
      }
      const f16* hbase = hb + (16 * w + lr) * 16 + (kg & 1) * 8 + (kg >> 1) * 1024;
      f16x8 frag[32];
#pragma unroll
      for (int kc = 0; kc < 32; ++kc) frag[kc] = *(const f16x8*)(hbase + kc * 2048);
#pragma unroll
      for (int kc = 0; kc < 32; ++kc) {
        int ko = kc * 32 + kg * 8;
        ar = __builtin_amdgcn_mfma_f32_16x16x32_f16(frag[kc], *(const f16x8*)(wr_ + ko), ar, 0, 0, 0);
        az = __builtin_amdgcn_mfma_f32_16x16x32_f16(frag[kc], *(const f16x8*)(wz_ + ko), az, 0, 0, 0);
        an = __builtin_amdgcn_mfma_f32_16x16x32_f16(frag[kc], *(const f16x8*)(wn_ + ko), an, 0, 0, 0);
      }
    }
    f16 hv4[4];
#pragma unroll
    for (int r = 0; r < 4; ++r) {
      float xr = (float)px[0][r], xz = (float)px[1][r], xn = (float)px[2][r];
      float rr = 1.f / (1.f + __expf(-(xr + ar[r] + br)));
      float zz = 1.f / (1.f + __expf(-(xz + az[r] + bz)));
      float pre = xn + rr * (an[r] + bn);
      float nn = 2.f / (1.f + __expf(-2.f * pre)) - 1.f;   // tanh
      float hv = (1.f - zz) * nn + zz * hp4[r];
      hv4[r] = (f16)hv;
      hp4[r] = (float)hv4[r];
      hstage[mq + r][lr] = hv4[r];
    }
    __syncthreads();                 // hstage complete
    {
      f16* hbn = hbuf + ((t & 1) ? (size_t)(NBATCH * HID) : 0) + g * 1024;
      *(u64*)(hbn + ms * 16 + seg4) = *(const u64*)&hstage[ms][seg4];
    }
    __syncthreads();                 // all waves' h stores vmcnt-drained
    if (tid == 0) {
      __builtin_amdgcn_fence(__ATOMIC_RELEASE, "agent");   // wbL2: h visible at MALL
      __hip_atomic_store(&flags[g * FS], base + t + 1, __ATOMIC_RELAXED,
                         __HIP_MEMORY_SCOPE_AGENT);
    }
    // off critical path: layer-output store + next-step xgT prefetch
    f16* xrow = xseq + (size_t)t * (NBATCH * HID);
#pragma unroll
    for (int r = 0; r < 4; ++r) xrow[(mq + r) * HID + j] = hv4[r];
    if (tt + 1 < T) {
      const int mq2 = (tt + 1) * 64 + mq;
#pragma unroll
      for (int gt = 0; gt < 3; ++gt)
        px[gt] = *(const f16x4*)&xgT[(size_t)((gt << 10) + j) * LDT + mq2];
    }
  }
}

// ---------------- launch ----------------

extern "C" void kernel_launch(void* const* d_in, const int* in_sizes, int n_in,
                              void* d_out, int out_size, void* d_ws, size_t ws_size,
                              hipStream_t stream) {
  const float* in   = (const float*)d_in[0];
  const float* embW = (const float*)d_in[1];
  const float* embB = (const float*)d_in[2];
  const float* wih  = (const float*)d_in[3];
  const float* whh  = (const float*)d_in[4];
  const float* bih  = (const float*)d_in[5];
  const float* bhh  = (const float*)d_in[6];
  const float* outW = (const float*)d_in[7];
  const float* outB = (const float*)d_in[8];
  float* out = (float*)d_out;

  char* ws = (char*)d_ws;
  size_t off = 0;
  auto alloc = [&](size_t bytes) -> void* {
    void* p = ws + off; off += (bytes + 255) & ~(size_t)255; return p;
  };
  f16* whhL   = (f16*)alloc((size_t)G3 * HID * 2);    // 6 MB, re-converted per layer
  f16* wihL   = (f16*)alloc((size_t)G3 * HID * 2);    // 6 MB, layers 1,2
  f16* w016   = (f16*)alloc((size_t)G3 * KPAD * 2);
  f16* outw16 = (f16*)alloc(128UL * HID * 2);
  float* b0   = (float*)alloc((size_t)G3 * 4);
  f16* in16   = (f16*)alloc((size_t)MALL_M * KPAD * 2); // 4 MB
  f16* xseq   = (f16*)alloc((size_t)MALL_M * HID * 2);  // 64 MB, in-place across layers
  f16* hbuf   = (f16*)alloc(2UL * NBATCH * HID * 2);    // 256 KB ping-pong
  int* flags  = (int*)alloc(64UL * FS * 4);             // 8 KB per-block flags
  size_t fixed = off;

  int T = 128;
  while (T > 2 && fixed + ((size_t)T * NBATCH * G3 * 2 + 256) > ws_size) T >>= 1;
  f16* xgT = (f16*)alloc((size_t)T * NBATCH * G3 * 2);   // [3072][T*64]
  if (off > ws_size) return;
  const int NCHUNK = SEQL / T;
  const int LDT = T * NBATCH;

  // ---- prep ----
  k_zero<<<(64 * FS + 255) / 256, 256, 0, stream>>>(flags, 64 * FS);
  k_outw_pad<<<512, 256, 0, stream>>>(outW, outw16);
  k_cvt_in<<<(MALL_M * KPAD + 255) / 256, 256, 0, stream>>>(in, in16);
  k_prep_w0<<<(G3 * KPAD + 255) / 256, 256, 0, stream>>>(wih, embW, w016);
  k_prep_b0<<<(G3 + 255) / 256, 256, 0, stream>>>(wih, embB, bih, b0);

  for (int l = 0; l < 3; ++l) {
    k_cvt<<<2048, 256, 0, stream>>>(whh + (size_t)l * G3 * HID, whhL, (long)G3 * HID);
    if (l > 0)
      k_cvt<<<2048, 256, 0, stream>>>(wih + (size_t)l * G3 * EMB, wihL, (long)G3 * HID);

    for (int c = 0; c < NCHUNK; ++c) {
      if (l == 0)
        k_gemm<<<dim3(T * NBATCH / 128, G3 / 128), 256, 0, stream>>>(
            in16 + (size_t)c * T * NBATCH * KPAD, w016, b0,
            nullptr, xgT, nullptr, KPAD, G3, LDT);
      else
        k_gemm<<<dim3(T * NBATCH / 128, G3 / 128), 256, 0, stream>>>(
            xseq + (size_t)c * T * NBATCH * HID, wihL, bih + l * G3,
            nullptr, xgT, nullptr, HID, G3, LDT);
      k_rnn<<<64, 256, 0, stream>>>(xseq, hbuf, xgT, whhL, bhh + l * G3,
                                    c * T, T, LDT, l * SEQL, flags);
    }
  }
  // logits = xseq @ out_W^T + out_b (fp32 out)
  k_gemm<<<dim3(MALL_M / 128, 1), 256, 0, stream>>>(xseq, outw16, outB,
                                                    nullptr, nullptr, out, HID, NCLS, NCLS);
}